// Round 8
// baseline (398.422 us; speedup 1.0000x reference)
//
#include <hip/hip_runtime.h>

#define N_NODES 50000
#define N_EDGES 800000
#define F_IN 56
#define F_PAD 64
#define F_OUT 256
#define NB 32       // nodes per k_final block
#define ELL_W 64    // slots per node; deg+1 max ~37 for Poisson(16)
#define SEG_SZ 6250 // N_NODES / 8 destination segments (one per XCD)

// ---- fill: XCD-segmented degree count + ELL placement ----------------------
// block b owns segment b&7; with round-robin block->XCD dispatch each 1.6 MB
// ELL window is written by ONE XCD -> L2-absorbed, sequential-ish writeback.

__global__ __launch_bounds__(256) void k_fill(const int* __restrict__ ei,
                                              int* __restrict__ cnt,
                                              int* __restrict__ ell) {
  int seg = blockIdx.x & 7;
  int chunk = blockIdx.x >> 3;
  int nchunks = gridDim.x >> 3;
  int stride = nchunks * blockDim.x;
  for (int e = chunk * blockDim.x + threadIdx.x; e < N_EDGES; e += stride) {
    int d = ei[N_EDGES + e];
    if (d / SEG_SZ == seg) {
      int s = ei[e];
      int pos = atomicAdd(&cnt[d], 1);
      ell[(d << 6) + pos] = s;
    }
  }
}

// ---- dinv + deg + self-loop slot -------------------------------------------

__global__ void k_dinv(const int* __restrict__ cnt, float* __restrict__ dinv,
                       int* __restrict__ deg, int* __restrict__ ell) {
  int i = blockIdx.x * blockDim.x + threadIdx.x;
  if (i >= N_NODES) return;
  int c = cnt[i];
  dinv[i] = rsqrtf((float)(c + 1));
  deg[i] = c + 1;
  ell[(i << 6) + c] = i;  // self loop in last used slot
}

// ---- feature init: x padded to 64 cols, ones-vector in col 56 -------------

__global__ void k_loadx(const float* __restrict__ x, float* __restrict__ h) {
  int i = blockIdx.x * blockDim.x + threadIdx.x;  // N*64 threads
  int nn = i >> 6, f = i & 63;
  float v = 0.f;
  if (f < F_IN) v = x[nn * F_IN + f];
  else if (f == F_IN) v = 1.f;
  h[i] = v;
}

// ---- one hop: wave per node, 4 edge-rows per dwordx4 gather, 4 in flight --

__global__ __launch_bounds__(256) void k_hop(const float* __restrict__ hin,
                                             float* __restrict__ hout,
                                             const int* __restrict__ deg,
                                             const int* __restrict__ ell,
                                             const float* __restrict__ dinv,
                                             float* __restrict__ vsave) {
  int node = (blockIdx.x * blockDim.x + threadIdx.x) >> 6;
  int lane = threadIdx.x & 63;
  int d = __builtin_amdgcn_readfirstlane(deg[node]);  // includes self loop, >=1
  int rec = ell[((size_t)node << 6) + lane];          // one coalesced 256B row load
  rec = (lane < d) ? rec : node;                      // safe address for pad slots
  float dn = __int_as_float(__builtin_amdgcn_readfirstlane(
      __float_as_int(dinv[node])));
  float wl = (lane < d) ? dinv[rec] * dn : 0.f;       // pad slots weight 0

  int sub = lane >> 4;          // which of the 4 edges this lane serves
  int fo  = (lane & 15) << 2;   // feature offset within row (0,4,...,60)
  float4 acc = make_float4(0.f, 0.f, 0.f, 0.f);

  int ngroups = (d + 3) >> 2;   // groups of 4 edges (zero-weight padded)
  int g = 0;
  for (; g + 4 <= ngroups; g += 4) {          // 4 gathers in flight
    int   s0 = __shfl(rec, g * 4 + sub);
    float w0 = __shfl(wl,  g * 4 + sub);
    int   s1 = __shfl(rec, g * 4 + 4 + sub);
    float w1 = __shfl(wl,  g * 4 + 4 + sub);
    int   s2 = __shfl(rec, g * 4 + 8 + sub);
    float w2 = __shfl(wl,  g * 4 + 8 + sub);
    int   s3 = __shfl(rec, g * 4 + 12 + sub);
    float w3 = __shfl(wl,  g * 4 + 12 + sub);
    float4 a0 = *(const float4*)(hin + (((size_t)s0) << 6) + fo);
    float4 a1 = *(const float4*)(hin + (((size_t)s1) << 6) + fo);
    float4 a2 = *(const float4*)(hin + (((size_t)s2) << 6) + fo);
    float4 a3 = *(const float4*)(hin + (((size_t)s3) << 6) + fo);
    acc.x = fmaf(w0, a0.x, acc.x); acc.y = fmaf(w0, a0.y, acc.y);
    acc.z = fmaf(w0, a0.z, acc.z); acc.w = fmaf(w0, a0.w, acc.w);
    acc.x = fmaf(w1, a1.x, acc.x); acc.y = fmaf(w1, a1.y, acc.y);
    acc.z = fmaf(w1, a1.z, acc.z); acc.w = fmaf(w1, a1.w, acc.w);
    acc.x = fmaf(w2, a2.x, acc.x); acc.y = fmaf(w2, a2.y, acc.y);
    acc.z = fmaf(w2, a2.z, acc.z); acc.w = fmaf(w2, a2.w, acc.w);
    acc.x = fmaf(w3, a3.x, acc.x); acc.y = fmaf(w3, a3.y, acc.y);
    acc.z = fmaf(w3, a3.z, acc.z); acc.w = fmaf(w3, a3.w, acc.w);
  }
  for (; g < ngroups; ++g) {
    int   s0 = __shfl(rec, g * 4 + sub);
    float w0 = __shfl(wl,  g * 4 + sub);
    float4 a0 = *(const float4*)(hin + (((size_t)s0) << 6) + fo);
    acc.x = fmaf(w0, a0.x, acc.x); acc.y = fmaf(w0, a0.y, acc.y);
    acc.z = fmaf(w0, a0.z, acc.z); acc.w = fmaf(w0, a0.w, acc.w);
  }
  // reduce the 4 edge subgroups (lanes l, l^16, l^32, l^48)
  acc.x += __shfl_xor(acc.x, 16);
  acc.y += __shfl_xor(acc.y, 16);
  acc.z += __shfl_xor(acc.z, 16);
  acc.w += __shfl_xor(acc.w, 16);
  acc.x += __shfl_xor(acc.x, 32);
  acc.y += __shfl_xor(acc.y, 32);
  acc.z += __shfl_xor(acc.z, 32);
  acc.w += __shfl_xor(acc.w, 32);

  if (lane < 16) {
    *(float4*)(hout + ((size_t)node << 6) + fo) = acc;
  }
  if (vsave != nullptr && lane == 14) vsave[node] = acc.x;  // feature 56 = A^k·1
}

// ---- collapse weights: M = W1W2W3W4; c1=b1'W2W3W4; c2=b2'W3W4; c3=b3'W4+b4

__global__ void k_weights(const float* __restrict__ W1, const float* __restrict__ b1,
                          const float* __restrict__ W2, const float* __restrict__ b2,
                          const float* __restrict__ W3, const float* __restrict__ b3,
                          const float* __restrict__ W4, const float* __restrict__ b4,
                          float* __restrict__ Mw, float* __restrict__ c1,
                          float* __restrict__ c2, float* __restrict__ c3) {
  __shared__ float t1[64], t2[64], t3[64];
  int m = blockIdx.x, tid = threadIdx.x;
  if (m < F_IN) {  // row m of M: ((W1[m,:]W2)W3)W4
    if (tid < 64) {
      float a = 0.f;
      for (int k = 0; k < 64; ++k) a = fmaf(W1[m * 64 + k], W2[k * 64 + tid], a);
      t1[tid] = a;
    }
    __syncthreads();
    if (tid < 64) {
      float a = 0.f;
      for (int k = 0; k < 64; ++k) a = fmaf(t1[k], W3[k * 64 + tid], a);
      t2[tid] = a;
    }
    __syncthreads();
    {
      float a = 0.f;
      for (int k = 0; k < 64; ++k) a = fmaf(t2[k], W4[k * 256 + tid], a);
      Mw[m * 256 + tid] = a;
    }
  } else {  // bias chains
    if (tid < 64) {
      float a = 0.f;
      for (int k = 0; k < 64; ++k) a = fmaf(b1[k], W2[k * 64 + tid], a);
      t1[tid] = a;
    }
    __syncthreads();
    if (tid < 64) {
      float a = 0.f, b = 0.f;
      for (int k = 0; k < 64; ++k) {
        float w3 = W3[k * 64 + tid];
        a = fmaf(t1[k], w3, a);
        b = fmaf(b2[k], w3, b);
      }
      t2[tid] = a; t3[tid] = b;
    }
    __syncthreads();
    {
      float a = 0.f, b = 0.f, c = 0.f;
      for (int k = 0; k < 64; ++k) {
        float w4 = W4[k * 256 + tid];
        a = fmaf(t2[k], w4, a);
        b = fmaf(t3[k], w4, b);
        c = fmaf(b3[k], w4, c);
      }
      c1[tid] = a; c2[tid] = b; c3[tid] = c + b4[tid];
    }
  }
}

// ---- epilogue: out = y@M + v6*c1 + v3*c2 + c3 -----------------------------
// thread j owns output col j; M[:,j] in 56 registers; 2 nodes x 4 partial
// accumulators = 8 independent FMA chains (breaks the 56-long dep chain).

__global__ __launch_bounds__(256) void k_final(const float* __restrict__ y,
                                               const float* __restrict__ v3,
                                               const float* __restrict__ v6,
                                               const float* __restrict__ Mw,
                                               const float* __restrict__ c1,
                                               const float* __restrict__ c2,
                                               const float* __restrict__ c3,
                                               float* __restrict__ out) {
  __shared__ float4 yl[NB][16];          // 8.2 KB
  __shared__ float v3l[NB], v6l[NB];
  int tid = threadIdx.x;
  int j = tid;                           // output column

  float4 Mreg[14];                       // M[:, j] — 56 VGPRs
#pragma unroll
  for (int k4 = 0; k4 < 14; ++k4) {
    Mreg[k4].x = Mw[(k4 * 4 + 0) * F_OUT + j];
    Mreg[k4].y = Mw[(k4 * 4 + 1) * F_OUT + j];
    Mreg[k4].z = Mw[(k4 * 4 + 2) * F_OUT + j];
    Mreg[k4].w = Mw[(k4 * 4 + 3) * F_OUT + j];
  }
  float C1 = c1[j], C2 = c2[j], C3 = c3[j];

  int n0 = blockIdx.x * NB;
  int lim = min(NB, N_NODES - n0);
  for (int i = tid; i < lim * 16; i += 256) {
    int nn = i >> 4, q = i & 15;
    yl[nn][q] = *(const float4*)(y + ((size_t)(n0 + nn) << 6) + q * 4);
  }
  if (tid < lim) { v3l[tid] = v3[n0 + tid]; v6l[tid] = v6[n0 + tid]; }
  __syncthreads();

  for (int nn = 0; nn < lim; nn += 2) {
    bool two = (nn + 1) < lim;
    float a0 = fmaf(v6l[nn], C1, fmaf(v3l[nn], C2, C3));
    float a1 = 0.f, a2 = 0.f, a3 = 0.f;
    int nn2 = two ? nn + 1 : nn;
    float b0 = fmaf(v6l[nn2], C1, fmaf(v3l[nn2], C2, C3));
    float b1v = 0.f, b2v = 0.f, b3v = 0.f;
#pragma unroll
    for (int k4 = 0; k4 < 14; ++k4) {
      float4 ya = yl[nn][k4];
      float4 yb = yl[nn2][k4];
      a0  = fmaf(ya.x, Mreg[k4].x, a0);
      a1  = fmaf(ya.y, Mreg[k4].y, a1);
      a2  = fmaf(ya.z, Mreg[k4].z, a2);
      a3  = fmaf(ya.w, Mreg[k4].w, a3);
      b0  = fmaf(yb.x, Mreg[k4].x, b0);
      b1v = fmaf(yb.y, Mreg[k4].y, b1v);
      b2v = fmaf(yb.z, Mreg[k4].z, b2v);
      b3v = fmaf(yb.w, Mreg[k4].w, b3v);
    }
    out[(size_t)(n0 + nn) * F_OUT + j] = (a0 + a1) + (a2 + a3);
    if (two) out[(size_t)(n0 + nn + 1) * F_OUT + j] = (b0 + b1v) + (b2v + b3v);
  }
}

// ---- launch ---------------------------------------------------------------

extern "C" void kernel_launch(void* const* d_in, const int* in_sizes, int n_in,
                              void* d_out, int out_size, void* d_ws, size_t ws_size,
                              hipStream_t stream) {
  const float* x  = (const float*)d_in[0];
  const int*   ei = (const int*)d_in[1];
  const float* W1 = (const float*)d_in[2];
  const float* b1 = (const float*)d_in[3];
  const float* W2 = (const float*)d_in[4];
  const float* b2 = (const float*)d_in[5];
  const float* W3 = (const float*)d_in[6];
  const float* b3 = (const float*)d_in[7];
  const float* W4 = (const float*)d_in[8];
  const float* b4 = (const float*)d_in[9];
  float* out = (float*)d_out;

  char* ws = (char*)d_ws;
  size_t off = 0;
  auto take = [&](size_t bytes) -> void* {
    void* p = ws + off;
    off += (bytes + 255) & ~(size_t)255;
    return p;
  };
  int*   cnt   = (int*)take((size_t)N_NODES * 4);
  int*   deg   = (int*)take((size_t)N_NODES * 4);
  float* dinv  = (float*)take((size_t)N_NODES * 4);
  float* v3    = (float*)take((size_t)N_NODES * 4);
  float* v6    = (float*)take((size_t)N_NODES * 4);
  int*   ell   = (int*)take((size_t)N_NODES * ELL_W * 4);   // 12.8 MB
  float* hA    = (float*)take((size_t)N_NODES * F_PAD * 4); // 12.8 MB
  float* hB    = (float*)take((size_t)N_NODES * F_PAD * 4); // 12.8 MB
  float* Mw    = (float*)take((size_t)F_IN * F_OUT * 4);
  float* c1    = (float*)take((size_t)F_OUT * 4);
  float* c2    = (float*)take((size_t)F_OUT * 4);
  float* c3    = (float*)take((size_t)F_OUT * 4);

  (void)hipMemsetAsync(cnt, 0, (size_t)N_NODES * 4, stream);
  k_fill<<<1024, 256, 0, stream>>>(ei, cnt, ell);  // 8 segs x 128 chunks
  k_dinv<<<(N_NODES + 255) / 256, 256, 0, stream>>>(cnt, dinv, deg, ell);
  k_loadx<<<(N_NODES * F_PAD) / 256, 256, 0, stream>>>(x, hA);
  k_weights<<<F_IN + 1, 256, 0, stream>>>(W1, b1, W2, b2, W3, b3, W4, b4, Mw, c1, c2, c3);

  float* src = hA;
  float* dst = hB;
  for (int hop = 1; hop <= 9; ++hop) {
    float* vs = (hop == 3) ? v3 : (hop == 6) ? v6 : nullptr;
    k_hop<<<(N_NODES * F_PAD) / 256, 256, 0, stream>>>(src, dst, deg, ell, dinv, vs);
    float* t = src; src = dst; dst = t;
  }
  k_final<<<(N_NODES + NB - 1) / NB, 256, 0, stream>>>(src, v3, v6, Mw, c1, c2, c3, out);
}

// Round 9
// 363.280 us; speedup vs baseline: 1.0967x; 1.0967x over previous
//
#include <hip/hip_runtime.h>

#define N_NODES 50000
#define N_EDGES 800000
#define F_IN 56
#define F_PAD 64
#define F_OUT 256
#define NB 32       // nodes per k_final block
#define ELL_W 64    // slots per node; deg+1 max ~37 for Poisson(16)
#define SEG_SZ 6250 // N_NODES / 8 destination segments (one per XCD)
#define ZROW N_NODES  // index of the always-zero row in hA/hB

// ---- fill: XCD-segmented degree count + ELL placement ----------------------

__global__ __launch_bounds__(256) void k_fill(const int* __restrict__ ei,
                                              int* __restrict__ cnt,
                                              int* __restrict__ ell) {
  int seg = blockIdx.x & 7;
  int chunk = blockIdx.x >> 3;
  int nchunks = gridDim.x >> 3;
  int stride = nchunks * blockDim.x;
  for (int e = chunk * blockDim.x + threadIdx.x; e < N_EDGES; e += stride) {
    int d = ei[N_EDGES + e];
    if (d / SEG_SZ == seg) {
      int s = ei[e];
      int pos = atomicAdd(&cnt[d], 1);
      ell[(d << 6) + pos] = s;
    }
  }
}

// ---- prep: dinv, ideg, sqd, deg, self-loop slot ----------------------------

__global__ void k_prep(const int* __restrict__ cnt, float* __restrict__ dinv,
                       float* __restrict__ ideg, float* __restrict__ sqd,
                       int* __restrict__ deg, int* __restrict__ ell) {
  int i = blockIdx.x * blockDim.x + threadIdx.x;
  if (i >= N_NODES) return;
  int c = cnt[i] + 1;                 // deg incl. self loop, >=1
  float fc = (float)c;
  dinv[i] = rsqrtf(fc);
  ideg[i] = 1.0f / fc;
  sqd[i]  = sqrtf(fc);
  deg[i] = c;
  ell[(i << 6) + (c - 1)] = i;        // self loop in last used slot
}

// ---- feature init: u0 = dinv * [x | 1 | 0pad], 64 cols ---------------------

__global__ void k_loadx(const float* __restrict__ x, const float* __restrict__ dinv,
                        float* __restrict__ h) {
  int i = blockIdx.x * blockDim.x + threadIdx.x;  // N*64 threads
  int nn = i >> 6, f = i & 63;
  float di = dinv[nn];
  float v = 0.f;
  if (f < F_IN) v = x[nn * F_IN + f] * di;
  else if (f == F_IN) v = di;        // ones column in u-space
  h[i] = v;
}

// ---- one hop in u-space: UNWEIGHTED gather-sum, then * 1/deg ---------------
// wave per node; lane = (edge subgroup: lane>>4) x (feature quad); pad slots
// redirect to the always-zero row ZROW.

__global__ __launch_bounds__(256) void k_hop(const float* __restrict__ hin,
                                             float* __restrict__ hout,
                                             const int* __restrict__ deg,
                                             const int* __restrict__ ell,
                                             const float* __restrict__ ideg,
                                             float* __restrict__ vsave) {
  int node = (blockIdx.x * blockDim.x + threadIdx.x) >> 6;
  int lane = threadIdx.x & 63;
  int d = __builtin_amdgcn_readfirstlane(deg[node]);
  int rec = ell[((size_t)node << 6) + lane];      // coalesced 256B row load
  rec = (lane < d) ? rec : ZROW;                  // pads read the zero row
  float idg = __int_as_float(__builtin_amdgcn_readfirstlane(
      __float_as_int(ideg[node])));

  int sub = lane >> 4;          // which of the 4 edges this lane serves
  int fo  = (lane & 15) << 2;   // feature offset within row (0,4,...,60)
  float4 acc = make_float4(0.f, 0.f, 0.f, 0.f);

  int ngroups = (d + 3) >> 2;   // groups of 4 edges (zero-row padded)
  int g = 0;
  for (; g + 4 <= ngroups; g += 4) {          // 4 gathers in flight, 4 shfl/16 edges
    int s0 = __shfl(rec, g * 4 + sub);
    int s1 = __shfl(rec, g * 4 + 4 + sub);
    int s2 = __shfl(rec, g * 4 + 8 + sub);
    int s3 = __shfl(rec, g * 4 + 12 + sub);
    float4 a0 = *(const float4*)(hin + (((size_t)s0) << 6) + fo);
    float4 a1 = *(const float4*)(hin + (((size_t)s1) << 6) + fo);
    float4 a2 = *(const float4*)(hin + (((size_t)s2) << 6) + fo);
    float4 a3 = *(const float4*)(hin + (((size_t)s3) << 6) + fo);
    acc.x += (a0.x + a1.x) + (a2.x + a3.x);
    acc.y += (a0.y + a1.y) + (a2.y + a3.y);
    acc.z += (a0.z + a1.z) + (a2.z + a3.z);
    acc.w += (a0.w + a1.w) + (a2.w + a3.w);
  }
  for (; g < ngroups; ++g) {
    int s0 = __shfl(rec, g * 4 + sub);
    float4 a0 = *(const float4*)(hin + (((size_t)s0) << 6) + fo);
    acc.x += a0.x; acc.y += a0.y; acc.z += a0.z; acc.w += a0.w;
  }
  // reduce the 4 edge subgroups (lanes l, l^16, l^32, l^48)
  acc.x += __shfl_xor(acc.x, 16);
  acc.y += __shfl_xor(acc.y, 16);
  acc.z += __shfl_xor(acc.z, 16);
  acc.w += __shfl_xor(acc.w, 16);
  acc.x += __shfl_xor(acc.x, 32);
  acc.y += __shfl_xor(acc.y, 32);
  acc.z += __shfl_xor(acc.z, 32);
  acc.w += __shfl_xor(acc.w, 32);

  acc.x *= idg; acc.y *= idg; acc.z *= idg; acc.w *= idg;

  if (lane < 16) {
    *(float4*)(hout + ((size_t)node << 6) + fo) = acc;
  }
  if (vsave != nullptr && lane == 14) vsave[node] = acc.x;  // u-space col 56
}

// ---- collapse weights: M = W1W2W3W4; c1=b1'W2W3W4; c2=b2'W3W4; c3=b3'W4+b4

__global__ void k_weights(const float* __restrict__ W1, const float* __restrict__ b1,
                          const float* __restrict__ W2, const float* __restrict__ b2,
                          const float* __restrict__ W3, const float* __restrict__ b3,
                          const float* __restrict__ W4, const float* __restrict__ b4,
                          float* __restrict__ Mw, float* __restrict__ c1,
                          float* __restrict__ c2, float* __restrict__ c3) {
  __shared__ float t1[64], t2[64], t3[64];
  int m = blockIdx.x, tid = threadIdx.x;
  if (m < F_IN) {  // row m of M: ((W1[m,:]W2)W3)W4
    if (tid < 64) {
      float a = 0.f;
      for (int k = 0; k < 64; ++k) a = fmaf(W1[m * 64 + k], W2[k * 64 + tid], a);
      t1[tid] = a;
    }
    __syncthreads();
    if (tid < 64) {
      float a = 0.f;
      for (int k = 0; k < 64; ++k) a = fmaf(t1[k], W3[k * 64 + tid], a);
      t2[tid] = a;
    }
    __syncthreads();
    {
      float a = 0.f;
      for (int k = 0; k < 64; ++k) a = fmaf(t2[k], W4[k * 256 + tid], a);
      Mw[m * 256 + tid] = a;
    }
  } else {  // bias chains
    if (tid < 64) {
      float a = 0.f;
      for (int k = 0; k < 64; ++k) a = fmaf(b1[k], W2[k * 64 + tid], a);
      t1[tid] = a;
    }
    __syncthreads();
    if (tid < 64) {
      float a = 0.f, b = 0.f;
      for (int k = 0; k < 64; ++k) {
        float w3 = W3[k * 64 + tid];
        a = fmaf(t1[k], w3, a);
        b = fmaf(b2[k], w3, b);
      }
      t2[tid] = a; t3[tid] = b;
    }
    __syncthreads();
    {
      float a = 0.f, b = 0.f, c = 0.f;
      for (int k = 0; k < 64; ++k) {
        float w4 = W4[k * 256 + tid];
        a = fmaf(t2[k], w4, a);
        b = fmaf(t3[k], w4, b);
        c = fmaf(b3[k], w4, c);
      }
      c1[tid] = a; c2[tid] = b; c3[tid] = c + b4[tid];
    }
  }
}

// ---- epilogue: out = (sqd*y)@M + v6*c1 + v3*c2 + c3 ------------------------
// thread j owns output col j; M[:,j] in 56 registers; 4 independent FMA chains

__global__ __launch_bounds__(256) void k_final(const float* __restrict__ y,
                                               const float* __restrict__ v3u,
                                               const float* __restrict__ v6u,
                                               const float* __restrict__ sqd,
                                               const float* __restrict__ Mw,
                                               const float* __restrict__ c1,
                                               const float* __restrict__ c2,
                                               const float* __restrict__ c3,
                                               float* __restrict__ out) {
  __shared__ float4 yl[NB][16];          // 8.2 KB
  __shared__ float v3l[NB], v6l[NB];
  int tid = threadIdx.x;
  int j = tid;                           // output column

  float4 Mreg[14];                       // M[:, j] — 56 VGPRs
#pragma unroll
  for (int k4 = 0; k4 < 14; ++k4) {
    Mreg[k4].x = Mw[(k4 * 4 + 0) * F_OUT + j];
    Mreg[k4].y = Mw[(k4 * 4 + 1) * F_OUT + j];
    Mreg[k4].z = Mw[(k4 * 4 + 2) * F_OUT + j];
    Mreg[k4].w = Mw[(k4 * 4 + 3) * F_OUT + j];
  }
  float C1 = c1[j], C2 = c2[j], C3 = c3[j];

  int n0 = blockIdx.x * NB;
  int lim = min(NB, N_NODES - n0);
  for (int i = tid; i < lim * 16; i += 256) {
    int nn = i >> 4, q = i & 15;
    float sq = sqd[n0 + nn];             // back to h-space: y = sqd * u9
    float4 v = *(const float4*)(y + ((size_t)(n0 + nn) << 6) + q * 4);
    v.x *= sq; v.y *= sq; v.z *= sq; v.w *= sq;
    yl[nn][q] = v;
  }
  if (tid < lim) {
    float sq = sqd[n0 + tid];
    v3l[tid] = v3u[n0 + tid] * sq;
    v6l[tid] = v6u[n0 + tid] * sq;
  }
  __syncthreads();

  for (int nn = 0; nn < lim; ++nn) {
    float a0 = fmaf(v6l[nn], C1, fmaf(v3l[nn], C2, C3));
    float a1 = 0.f, a2 = 0.f, a3 = 0.f;
#pragma unroll
    for (int k4 = 0; k4 < 14; ++k4) {
      float4 yv = yl[nn][k4];
      a0 = fmaf(yv.x, Mreg[k4].x, a0);
      a1 = fmaf(yv.y, Mreg[k4].y, a1);
      a2 = fmaf(yv.z, Mreg[k4].z, a2);
      a3 = fmaf(yv.w, Mreg[k4].w, a3);
    }
    out[(size_t)(n0 + nn) * F_OUT + j] = (a0 + a1) + (a2 + a3);
  }
}

// ---- launch ---------------------------------------------------------------

extern "C" void kernel_launch(void* const* d_in, const int* in_sizes, int n_in,
                              void* d_out, int out_size, void* d_ws, size_t ws_size,
                              hipStream_t stream) {
  const float* x  = (const float*)d_in[0];
  const int*   ei = (const int*)d_in[1];
  const float* W1 = (const float*)d_in[2];
  const float* b1 = (const float*)d_in[3];
  const float* W2 = (const float*)d_in[4];
  const float* b2 = (const float*)d_in[5];
  const float* W3 = (const float*)d_in[6];
  const float* b3 = (const float*)d_in[7];
  const float* W4 = (const float*)d_in[8];
  const float* b4 = (const float*)d_in[9];
  float* out = (float*)d_out;

  char* ws = (char*)d_ws;
  size_t off = 0;
  auto take = [&](size_t bytes) -> void* {
    void* p = ws + off;
    off += (bytes + 255) & ~(size_t)255;
    return p;
  };
  int*   cnt   = (int*)take((size_t)N_NODES * 4);
  int*   deg   = (int*)take((size_t)N_NODES * 4);
  float* dinv  = (float*)take((size_t)N_NODES * 4);
  float* ideg  = (float*)take((size_t)N_NODES * 4);
  float* sqd   = (float*)take((size_t)N_NODES * 4);
  float* v3    = (float*)take((size_t)N_NODES * 4);
  float* v6    = (float*)take((size_t)N_NODES * 4);
  int*   ell   = (int*)take((size_t)N_NODES * ELL_W * 4);         // 12.8 MB
  float* hA    = (float*)take((size_t)(N_NODES + 1) * F_PAD * 4); // + zero row
  float* hB    = (float*)take((size_t)(N_NODES + 1) * F_PAD * 4);
  float* Mw    = (float*)take((size_t)F_IN * F_OUT * 4);
  float* c1    = (float*)take((size_t)F_OUT * 4);
  float* c2    = (float*)take((size_t)F_OUT * 4);
  float* c3    = (float*)take((size_t)F_OUT * 4);

  (void)hipMemsetAsync(cnt, 0, (size_t)N_NODES * 4, stream);
  (void)hipMemsetAsync(hA + (size_t)ZROW * F_PAD, 0, F_PAD * 4, stream);
  (void)hipMemsetAsync(hB + (size_t)ZROW * F_PAD, 0, F_PAD * 4, stream);
  k_fill<<<1024, 256, 0, stream>>>(ei, cnt, ell);  // 8 segs x 128 chunks
  k_prep<<<(N_NODES + 255) / 256, 256, 0, stream>>>(cnt, dinv, ideg, sqd, deg, ell);
  k_loadx<<<(N_NODES * F_PAD) / 256, 256, 0, stream>>>(x, dinv, hA);
  k_weights<<<F_IN + 1, 256, 0, stream>>>(W1, b1, W2, b2, W3, b3, W4, b4, Mw, c1, c2, c3);

  float* src = hA;
  float* dst = hB;
  for (int hop = 1; hop <= 9; ++hop) {
    float* vs = (hop == 3) ? v3 : (hop == 6) ? v6 : nullptr;
    k_hop<<<(N_NODES * F_PAD) / 256, 256, 0, stream>>>(src, dst, deg, ell, ideg, vs);
    float* t = src; src = dst; dst = t;
  }
  k_final<<<(N_NODES + NB - 1) / NB, 256, 0, stream>>>(src, v3, v6, sqd, Mw, c1, c2, c3, out);
}

// Round 10
// 357.630 us; speedup vs baseline: 1.1141x; 1.0158x over previous
//
#include <hip/hip_runtime.h>

#define N_NODES 50000
#define N_EDGES 800000
#define N_GROUPS 12500      // 4 nodes per group
#define GSLOTS 128          // slots per group; ~68+4 expected, 7σ margin
#define F_IN 56
#define F_PAD 64
#define F_OUT 256
#define NB 32               // nodes per k_final block
#define SEG_SZ 6250         // dst segment per XCD for k_fill
#define ZROW N_NODES        // always-zero row in hA/hB
#define PAD_E 0x7FFFFFFF

// ---- fill: XCD-segmented append into group-ELL -----------------------------

__global__ __launch_bounds__(256) void k_fill(const int* __restrict__ ei,
                                              int* __restrict__ gcnt,
                                              int* __restrict__ ellg) {
  int seg = blockIdx.x & 7;
  int chunk = blockIdx.x >> 3;
  int nchunks = gridDim.x >> 3;
  int stride = nchunks * blockDim.x;
  for (int e = chunk * blockDim.x + threadIdx.x; e < N_EDGES; e += stride) {
    int d = ei[N_EDGES + e];
    if (d / SEG_SZ == seg) {
      int s = ei[e];
      int g = d >> 2;
      int pos = atomicAdd(&gcnt[g], 1);
      ellg[(g << 7) + pos] = (s << 2) | (d & 3);
    }
  }
}

// ---- append self loops -----------------------------------------------------

__global__ void k_self(int* __restrict__ gcnt, int* __restrict__ ellg) {
  int i = blockIdx.x * blockDim.x + threadIdx.x;
  if (i >= N_NODES) return;
  int g = i >> 2;
  int pos = atomicAdd(&gcnt[g], 1);
  ellg[(g << 7) + pos] = (i << 2) | (i & 3);
}

// ---- per-group bitonic sort (128 entries, 2/lane) + degree calc ------------

__global__ __launch_bounds__(256) void k_sort(const int* __restrict__ gcnt,
                                              int* __restrict__ ellg,
                                              float* __restrict__ dinv,
                                              float* __restrict__ ideg,
                                              float* __restrict__ sqd) {
  int w = (blockIdx.x * blockDim.x + threadIdx.x) >> 6;  // group
  int l = threadIdx.x & 63;
  int cnt = __builtin_amdgcn_readfirstlane(gcnt[w]);
  int* base = ellg + ((size_t)w << 7);
  int v0 = (l < cnt) ? base[l] : PAD_E;
  int v1 = (64 + l < cnt) ? base[64 + l] : PAD_E;

#pragma unroll
  for (int k = 2; k <= 128; k <<= 1) {
#pragma unroll
    for (int j = 64; j > 0; j >>= 1) {
      if (j >= k) continue;
      if (j == 64) {                      // in-lane pair (i, i+64); k=128 -> up
        int lo = min(v0, v1), hi = max(v0, v1);
        v0 = lo; v1 = hi;
      } else {
        int o0 = __shfl_xor(v0, j);
        int o1 = __shfl_xor(v1, j);
        bool lower = ((l & j) == 0);
        bool up0 = ((l & k) == 0);
        bool up1 = (((l + 64) & k) == 0);
        v0 = (lower == up0) ? min(v0, o0) : max(v0, o0);
        v1 = (lower == up1) ? min(v1, o1) : max(v1, o1);
      }
    }
  }

  // degrees per dst-sub via ballot (self loops already appended)
  int c0 = __popcll(__ballot(v0 != PAD_E && (v0 & 3) == 0)) +
           __popcll(__ballot(v1 != PAD_E && (v1 & 3) == 0));
  int c1 = __popcll(__ballot(v0 != PAD_E && (v0 & 3) == 1)) +
           __popcll(__ballot(v1 != PAD_E && (v1 & 3) == 1));
  int c2 = __popcll(__ballot(v0 != PAD_E && (v0 & 3) == 2)) +
           __popcll(__ballot(v1 != PAD_E && (v1 & 3) == 2));
  int c3 = __popcll(__ballot(v0 != PAD_E && (v0 & 3) == 3)) +
           __popcll(__ballot(v1 != PAD_E && (v1 & 3) == 3));
  if (l < 4) {
    int c = (l == 0) ? c0 : (l == 1) ? c1 : (l == 2) ? c2 : c3;
    float fc = (float)c;
    int node = (w << 2) + l;
    dinv[node] = rsqrtf(fc);
    ideg[node] = 1.0f / fc;
    sqd[node]  = sqrtf(fc);
  }

  base[l] = (v0 == PAD_E) ? (ZROW << 2) : v0;        // pads -> zero row
  base[64 + l] = (v1 == PAD_E) ? (ZROW << 2) : v1;
}

// ---- feature init: u0 = dinv * [x | 1 | 0pad], 64 cols ---------------------

__global__ void k_loadx(const float* __restrict__ x, const float* __restrict__ dinv,
                        float* __restrict__ h) {
  int i = blockIdx.x * blockDim.x + threadIdx.x;  // N*64 threads
  int nn = i >> 6, f = i & 63;
  float di = dinv[nn];
  float v = 0.f;
  if (f < F_IN) v = x[nn * F_IN + f] * di;
  else if (f == F_IN) v = di;
  h[i] = v;
}

// ---- one hop: wave per 4-node group, src-sorted edge walk ------------------
// lane = (sub: lane>>4) x (feature quad m: lane&15). Edge quad g: sub handles
// edge 4g+sub; masked-FMA into 4 per-lane dst accumulators; pads hit ZROW.

__global__ __launch_bounds__(256) void k_hop(const float* __restrict__ hin,
                                             float* __restrict__ hout,
                                             const int* __restrict__ gcnt,
                                             const int* __restrict__ ellg,
                                             const float* __restrict__ ideg,
                                             float* __restrict__ vsave) {
  int w = (blockIdx.x * blockDim.x + threadIdx.x) >> 6;  // group
  int lane = threadIdx.x & 63;
  int sub = lane >> 4, m = lane & 15, fo = m << 2;
  int cnt = __builtin_amdgcn_readfirstlane(gcnt[w]);
  const int* base = ellg + ((size_t)w << 7);
  int rec0 = base[lane];          // slots 0..63   (coalesced 256B)
  int rec1 = base[64 + lane];     // slots 64..127
  float4 acc0 = make_float4(0.f, 0.f, 0.f, 0.f);
  float4 acc1 = acc0, acc2 = acc0, acc3 = acc0;
  int nq = (cnt + 3) >> 2;

#define GATHER(IDX, EV, AV)                                          \
  int EV = (IDX < 64) ? __shfl(rec0, IDX) : __shfl(rec1, IDX - 64);  \
  float4 AV = *(const float4*)(hin + (((size_t)(EV >> 2)) << 6) + fo);

#define ACCUM(EV, AV) {                                              \
    int dd = EV & 3;                                                 \
    float m0 = (dd == 0) ? 1.f : 0.f;                                \
    float m1 = (dd == 1) ? 1.f : 0.f;                                \
    float m2 = (dd == 2) ? 1.f : 0.f;                                \
    float m3 = (dd == 3) ? 1.f : 0.f;                                \
    acc0.x = fmaf(m0, AV.x, acc0.x); acc0.y = fmaf(m0, AV.y, acc0.y);\
    acc0.z = fmaf(m0, AV.z, acc0.z); acc0.w = fmaf(m0, AV.w, acc0.w);\
    acc1.x = fmaf(m1, AV.x, acc1.x); acc1.y = fmaf(m1, AV.y, acc1.y);\
    acc1.z = fmaf(m1, AV.z, acc1.z); acc1.w = fmaf(m1, AV.w, acc1.w);\
    acc2.x = fmaf(m2, AV.x, acc2.x); acc2.y = fmaf(m2, AV.y, acc2.y);\
    acc2.z = fmaf(m2, AV.z, acc2.z); acc2.w = fmaf(m2, AV.w, acc2.w);\
    acc3.x = fmaf(m3, AV.x, acc3.x); acc3.y = fmaf(m3, AV.y, acc3.y);\
    acc3.z = fmaf(m3, AV.z, acc3.z); acc3.w = fmaf(m3, AV.w, acc3.w);\
  }

  int g = 0;
  for (; g + 2 <= nq; g += 2) {
    int i0 = (g << 2) + sub;
    int i1 = i0 + 4;
    GATHER(i0, e0, a0)
    GATHER(i1, e1, a1)
    ACCUM(e0, a0)
    ACCUM(e1, a1)
  }
  if (g < nq) {
    int i0 = (g << 2) + sub;
    GATHER(i0, e0, a0)
    ACCUM(e0, a0)
  }
#undef GATHER
#undef ACCUM

  // reduce partial sums across the 4 sub groups (xor 16, 32)
#define RED(A) \
  A.x += __shfl_xor(A.x, 16); A.y += __shfl_xor(A.y, 16); \
  A.z += __shfl_xor(A.z, 16); A.w += __shfl_xor(A.w, 16); \
  A.x += __shfl_xor(A.x, 32); A.y += __shfl_xor(A.y, 32); \
  A.z += __shfl_xor(A.z, 32); A.w += __shfl_xor(A.w, 32);
  RED(acc0) RED(acc1) RED(acc2) RED(acc3)
#undef RED

  float4 v = (sub == 0) ? acc0 : (sub == 1) ? acc1 : (sub == 2) ? acc2 : acc3;
  int node = (w << 2) + sub;
  float idg = ideg[node];
  v.x *= idg; v.y *= idg; v.z *= idg; v.w *= idg;
  *(float4*)(hout + (((size_t)node) << 6) + fo) = v;
  if (vsave != nullptr && m == 14) vsave[node] = v.x;  // u-space col 56
}

// ---- collapse weights: M = W1W2W3W4; c1=b1'W2W3W4; c2=b2'W3W4; c3=b3'W4+b4

__global__ void k_weights(const float* __restrict__ W1, const float* __restrict__ b1,
                          const float* __restrict__ W2, const float* __restrict__ b2,
                          const float* __restrict__ W3, const float* __restrict__ b3,
                          const float* __restrict__ W4, const float* __restrict__ b4,
                          float* __restrict__ Mw, float* __restrict__ c1,
                          float* __restrict__ c2, float* __restrict__ c3) {
  __shared__ float t1[64], t2[64], t3[64];
  int m = blockIdx.x, tid = threadIdx.x;
  if (m < F_IN) {
    if (tid < 64) {
      float a = 0.f;
      for (int k = 0; k < 64; ++k) a = fmaf(W1[m * 64 + k], W2[k * 64 + tid], a);
      t1[tid] = a;
    }
    __syncthreads();
    if (tid < 64) {
      float a = 0.f;
      for (int k = 0; k < 64; ++k) a = fmaf(t1[k], W3[k * 64 + tid], a);
      t2[tid] = a;
    }
    __syncthreads();
    {
      float a = 0.f;
      for (int k = 0; k < 64; ++k) a = fmaf(t2[k], W4[k * 256 + tid], a);
      Mw[m * 256 + tid] = a;
    }
  } else {
    if (tid < 64) {
      float a = 0.f;
      for (int k = 0; k < 64; ++k) a = fmaf(b1[k], W2[k * 64 + tid], a);
      t1[tid] = a;
    }
    __syncthreads();
    if (tid < 64) {
      float a = 0.f, b = 0.f;
      for (int k = 0; k < 64; ++k) {
        float w3 = W3[k * 64 + tid];
        a = fmaf(t1[k], w3, a);
        b = fmaf(b2[k], w3, b);
      }
      t2[tid] = a; t3[tid] = b;
    }
    __syncthreads();
    {
      float a = 0.f, b = 0.f, c = 0.f;
      for (int k = 0; k < 64; ++k) {
        float w4 = W4[k * 256 + tid];
        a = fmaf(t2[k], w4, a);
        b = fmaf(t3[k], w4, b);
        c = fmaf(b3[k], w4, c);
      }
      c1[tid] = a; c2[tid] = b; c3[tid] = c + b4[tid];
    }
  }
}

// ---- epilogue: out = (sqd*y)@M + v6*c1 + v3*c2 + c3 ------------------------

__global__ __launch_bounds__(256) void k_final(const float* __restrict__ y,
                                               const float* __restrict__ v3u,
                                               const float* __restrict__ v6u,
                                               const float* __restrict__ sqd,
                                               const float* __restrict__ Mw,
                                               const float* __restrict__ c1,
                                               const float* __restrict__ c2,
                                               const float* __restrict__ c3,
                                               float* __restrict__ out) {
  __shared__ float4 yl[NB][16];
  __shared__ float v3l[NB], v6l[NB];
  int tid = threadIdx.x;
  int j = tid;

  float4 Mreg[14];
#pragma unroll
  for (int k4 = 0; k4 < 14; ++k4) {
    Mreg[k4].x = Mw[(k4 * 4 + 0) * F_OUT + j];
    Mreg[k4].y = Mw[(k4 * 4 + 1) * F_OUT + j];
    Mreg[k4].z = Mw[(k4 * 4 + 2) * F_OUT + j];
    Mreg[k4].w = Mw[(k4 * 4 + 3) * F_OUT + j];
  }
  float C1 = c1[j], C2 = c2[j], C3 = c3[j];

  int n0 = blockIdx.x * NB;
  int lim = min(NB, N_NODES - n0);
  for (int i = tid; i < lim * 16; i += 256) {
    int nn = i >> 4, q = i & 15;
    float sq = sqd[n0 + nn];
    float4 v = *(const float4*)(y + ((size_t)(n0 + nn) << 6) + q * 4);
    v.x *= sq; v.y *= sq; v.z *= sq; v.w *= sq;
    yl[nn][q] = v;
  }
  if (tid < lim) {
    float sq = sqd[n0 + tid];
    v3l[tid] = v3u[n0 + tid] * sq;
    v6l[tid] = v6u[n0 + tid] * sq;
  }
  __syncthreads();

  for (int nn = 0; nn < lim; ++nn) {
    float a0 = fmaf(v6l[nn], C1, fmaf(v3l[nn], C2, C3));
    float a1 = 0.f, a2 = 0.f, a3 = 0.f;
#pragma unroll
    for (int k4 = 0; k4 < 14; ++k4) {
      float4 yv = yl[nn][k4];
      a0 = fmaf(yv.x, Mreg[k4].x, a0);
      a1 = fmaf(yv.y, Mreg[k4].y, a1);
      a2 = fmaf(yv.z, Mreg[k4].z, a2);
      a3 = fmaf(yv.w, Mreg[k4].w, a3);
    }
    out[(size_t)(n0 + nn) * F_OUT + j] = (a0 + a1) + (a2 + a3);
  }
}

// ---- launch ---------------------------------------------------------------

extern "C" void kernel_launch(void* const* d_in, const int* in_sizes, int n_in,
                              void* d_out, int out_size, void* d_ws, size_t ws_size,
                              hipStream_t stream) {
  const float* x  = (const float*)d_in[0];
  const int*   ei = (const int*)d_in[1];
  const float* W1 = (const float*)d_in[2];
  const float* b1 = (const float*)d_in[3];
  const float* W2 = (const float*)d_in[4];
  const float* b2 = (const float*)d_in[5];
  const float* W3 = (const float*)d_in[6];
  const float* b3 = (const float*)d_in[7];
  const float* W4 = (const float*)d_in[8];
  const float* b4 = (const float*)d_in[9];
  float* out = (float*)d_out;

  char* ws = (char*)d_ws;
  size_t off = 0;
  auto take = [&](size_t bytes) -> void* {
    void* p = ws + off;
    off += (bytes + 255) & ~(size_t)255;
    return p;
  };
  int*   gcnt  = (int*)take((size_t)N_GROUPS * 4);
  float* dinv  = (float*)take((size_t)N_NODES * 4);
  float* ideg  = (float*)take((size_t)N_NODES * 4);
  float* sqd   = (float*)take((size_t)N_NODES * 4);
  float* v3    = (float*)take((size_t)N_NODES * 4);
  float* v6    = (float*)take((size_t)N_NODES * 4);
  int*   ellg  = (int*)take((size_t)N_GROUPS * GSLOTS * 4);       // 6.4 MB
  float* hA    = (float*)take((size_t)(N_NODES + 1) * F_PAD * 4); // + zero row
  float* hB    = (float*)take((size_t)(N_NODES + 1) * F_PAD * 4);
  float* Mw    = (float*)take((size_t)F_IN * F_OUT * 4);
  float* c1    = (float*)take((size_t)F_OUT * 4);
  float* c2    = (float*)take((size_t)F_OUT * 4);
  float* c3    = (float*)take((size_t)F_OUT * 4);

  (void)hipMemsetAsync(gcnt, 0, (size_t)N_GROUPS * 4, stream);
  (void)hipMemsetAsync(hA + (size_t)ZROW * F_PAD, 0, F_PAD * 4, stream);
  (void)hipMemsetAsync(hB + (size_t)ZROW * F_PAD, 0, F_PAD * 4, stream);
  k_fill<<<1024, 256, 0, stream>>>(ei, gcnt, ellg);
  k_self<<<(N_NODES + 255) / 256, 256, 0, stream>>>(gcnt, ellg);
  k_sort<<<(N_GROUPS * 64) / 256, 256, 0, stream>>>(gcnt, ellg, dinv, ideg, sqd);
  k_loadx<<<(N_NODES * F_PAD) / 256, 256, 0, stream>>>(x, dinv, hA);
  k_weights<<<F_IN + 1, 256, 0, stream>>>(W1, b1, W2, b2, W3, b3, W4, b4, Mw, c1, c2, c3);

  float* src = hA;
  float* dst = hB;
  for (int hop = 1; hop <= 9; ++hop) {
    float* vs = (hop == 3) ? v3 : (hop == 6) ? v6 : nullptr;
    k_hop<<<(N_GROUPS * 64) / 256, 256, 0, stream>>>(src, dst, gcnt, ellg, ideg, vs);
    float* t = src; src = dst; dst = t;
  }
  k_final<<<(N_NODES + NB - 1) / NB, 256, 0, stream>>>(src, v3, v6, sqd, Mw, c1, c2, c3, out);
}

// Round 11
// 350.993 us; speedup vs baseline: 1.1351x; 1.0189x over previous
//
#include <hip/hip_runtime.h>

#define N_NODES 50000
#define N_EDGES 800000
#define N_GROUPS 12500      // 4 nodes per group
#define HALF_G 6250         // groups per sweep generation
#define GSLOTS 128          // slots per group
#define F_IN 56
#define F_PAD 64
#define F_OUT 256
#define NB 16               // nodes per k_final block (50000 % 16 == 0)
#define SEG_SZ 6250         // dst segment per XCD for k_fill
#define ZROW N_NODES        // always-zero row in hA/hB
#define PAD_E 0x7FFFFFFF

// ---- fill: XCD-segmented append into group-ELL -----------------------------

__global__ __launch_bounds__(256) void k_fill(const int* __restrict__ ei,
                                              int* __restrict__ gcnt,
                                              int* __restrict__ ellg) {
  int seg = blockIdx.x & 7;
  int chunk = blockIdx.x >> 3;
  int nchunks = gridDim.x >> 3;
  int stride = nchunks * blockDim.x;
  for (int e = chunk * blockDim.x + threadIdx.x; e < N_EDGES; e += stride) {
    int d = ei[N_EDGES + e];
    if (d / SEG_SZ == seg) {
      int s = ei[e];
      int g = d >> 2;
      int pos = atomicAdd(&gcnt[g], 1);
      ellg[(g << 7) + pos] = (s << 2) | (d & 3);
    }
  }
}

// ---- append self loops -----------------------------------------------------

__global__ void k_self(int* __restrict__ gcnt, int* __restrict__ ellg) {
  int i = blockIdx.x * blockDim.x + threadIdx.x;
  if (i >= N_NODES) return;
  int g = i >> 2;
  int pos = atomicAdd(&gcnt[g], 1);
  ellg[(g << 7) + pos] = (i << 2) | (i & 3);
}

// ---- per-group bitonic sort (128 entries, 2/lane) + degree calc ------------

__global__ __launch_bounds__(256) void k_sort(const int* __restrict__ gcnt,
                                              int* __restrict__ ellg,
                                              float* __restrict__ dinv,
                                              float* __restrict__ ideg,
                                              float* __restrict__ sqd) {
  int w = (blockIdx.x * blockDim.x + threadIdx.x) >> 6;  // group
  int l = threadIdx.x & 63;
  int cnt = __builtin_amdgcn_readfirstlane(gcnt[w]);
  int* base = ellg + ((size_t)w << 7);
  int v0 = (l < cnt) ? base[l] : PAD_E;
  int v1 = (64 + l < cnt) ? base[64 + l] : PAD_E;

#pragma unroll
  for (int k = 2; k <= 128; k <<= 1) {
#pragma unroll
    for (int j = 64; j > 0; j >>= 1) {
      if (j >= k) continue;
      if (j == 64) {                      // in-lane pair (i, i+64); k=128 -> up
        int lo = min(v0, v1), hi = max(v0, v1);
        v0 = lo; v1 = hi;
      } else {
        int o0 = __shfl_xor(v0, j);
        int o1 = __shfl_xor(v1, j);
        bool lower = ((l & j) == 0);
        bool up0 = ((l & k) == 0);
        bool up1 = (((l + 64) & k) == 0);
        v0 = (lower == up0) ? min(v0, o0) : max(v0, o0);
        v1 = (lower == up1) ? min(v1, o1) : max(v1, o1);
      }
    }
  }

  // degrees per dst-sub via ballot (self loops already appended)
  int c0 = __popcll(__ballot(v0 != PAD_E && (v0 & 3) == 0)) +
           __popcll(__ballot(v1 != PAD_E && (v1 & 3) == 0));
  int c1 = __popcll(__ballot(v0 != PAD_E && (v0 & 3) == 1)) +
           __popcll(__ballot(v1 != PAD_E && (v1 & 3) == 1));
  int c2 = __popcll(__ballot(v0 != PAD_E && (v0 & 3) == 2)) +
           __popcll(__ballot(v1 != PAD_E && (v1 & 3) == 2));
  int c3 = __popcll(__ballot(v0 != PAD_E && (v0 & 3) == 3)) +
           __popcll(__ballot(v1 != PAD_E && (v1 & 3) == 3));
  if (l < 4) {
    int c = (l == 0) ? c0 : (l == 1) ? c1 : (l == 2) ? c2 : c3;
    float fc = (float)c;
    int node = (w << 2) + l;
    dinv[node] = rsqrtf(fc);
    ideg[node] = 1.0f / fc;
    sqd[node]  = sqrtf(fc);
  }

  base[l] = (v0 == PAD_E) ? (ZROW << 2) : v0;        // pads -> zero row
  base[64 + l] = (v1 == PAD_E) ? (ZROW << 2) : v1;
}

// ---- feature init: u0 = dinv * [x | 1 | 0pad], 64 cols ---------------------

__global__ void k_loadx(const float* __restrict__ x, const float* __restrict__ dinv,
                        float* __restrict__ h) {
  int i = blockIdx.x * blockDim.x + threadIdx.x;  // N*64 threads
  int nn = i >> 6, f = i & 63;
  float di = dinv[nn];
  float v = 0.f;
  if (f < F_IN) v = x[nn * F_IN + f] * di;
  else if (f == F_IN) v = di;
  h[i] = v;
}

// ---- one hop: persistent waves, boustrophedon src-sorted sweep -------------
// wave w handles group w ASCENDING then group w+HALF_G DESCENDING, so all
// ~6250 resident waves sweep src-space in lockstep: 0 -> 50K -> 0. The moving
// window stays L2-hot on every XCD.

template<bool ASC>
__device__ __forceinline__ void hop_group(int g, const float* __restrict__ hin,
                                          float* __restrict__ hout,
                                          const int* __restrict__ gcnt,
                                          const int* __restrict__ ellg,
                                          const float* __restrict__ ideg,
                                          float* __restrict__ vsave,
                                          int lane, int sub, int m, int fo) {
  int cnt = __builtin_amdgcn_readfirstlane(gcnt[g]);
  const int* base = ellg + ((size_t)g << 7);
  int rec0 = base[lane];          // slots 0..63   (coalesced 256B)
  int rec1 = base[64 + lane];     // slots 64..127
  float4 acc0 = make_float4(0.f, 0.f, 0.f, 0.f);
  float4 acc1 = acc0, acc2 = acc0, acc3 = acc0;
  int nq = (cnt + 3) >> 2;

#define GATHER(QI, EV, AV)                                                \
  int idx_##EV = ((QI) << 2) + sub;                                       \
  int EV = (idx_##EV < 64) ? __shfl(rec0, idx_##EV)                       \
                           : __shfl(rec1, idx_##EV - 64);                 \
  float4 AV = *(const float4*)(hin + (((size_t)(EV >> 2)) << 6) + fo);

#define ACCUM(EV, AV) {                                                   \
    int dd = EV & 3;                                                      \
    float m0 = (dd == 0) ? 1.f : 0.f;                                     \
    float m1 = (dd == 1) ? 1.f : 0.f;                                     \
    float m2 = (dd == 2) ? 1.f : 0.f;                                     \
    float m3 = (dd == 3) ? 1.f : 0.f;                                     \
    acc0.x = fmaf(m0, AV.x, acc0.x); acc0.y = fmaf(m0, AV.y, acc0.y);     \
    acc0.z = fmaf(m0, AV.z, acc0.z); acc0.w = fmaf(m0, AV.w, acc0.w);     \
    acc1.x = fmaf(m1, AV.x, acc1.x); acc1.y = fmaf(m1, AV.y, acc1.y);     \
    acc1.z = fmaf(m1, AV.z, acc1.z); acc1.w = fmaf(m1, AV.w, acc1.w);     \
    acc2.x = fmaf(m2, AV.x, acc2.x); acc2.y = fmaf(m2, AV.y, acc2.y);     \
    acc2.z = fmaf(m2, AV.z, acc2.z); acc2.w = fmaf(m2, AV.w, acc2.w);     \
    acc3.x = fmaf(m3, AV.x, acc3.x); acc3.y = fmaf(m3, AV.y, acc3.y);     \
    acc3.z = fmaf(m3, AV.z, acc3.z); acc3.w = fmaf(m3, AV.w, acc3.w);     \
  }

  int it = 0;
  for (; it + 2 <= nq; it += 2) {
    int q0 = ASC ? it : (nq - 1 - it);
    int q1 = ASC ? (it + 1) : (nq - 2 - it);
    GATHER(q0, e0, a0)
    GATHER(q1, e1, a1)
    ACCUM(e0, a0)
    ACCUM(e1, a1)
  }
  if (it < nq) {
    int q0 = ASC ? it : (nq - 1 - it);
    GATHER(q0, e0, a0)
    ACCUM(e0, a0)
  }
#undef GATHER
#undef ACCUM

#define RED(A) \
  A.x += __shfl_xor(A.x, 16); A.y += __shfl_xor(A.y, 16); \
  A.z += __shfl_xor(A.z, 16); A.w += __shfl_xor(A.w, 16); \
  A.x += __shfl_xor(A.x, 32); A.y += __shfl_xor(A.y, 32); \
  A.z += __shfl_xor(A.z, 32); A.w += __shfl_xor(A.w, 32);
  RED(acc0) RED(acc1) RED(acc2) RED(acc3)
#undef RED

  float4 v = (sub == 0) ? acc0 : (sub == 1) ? acc1 : (sub == 2) ? acc2 : acc3;
  int node = (g << 2) + sub;
  float idg = ideg[node];
  v.x *= idg; v.y *= idg; v.z *= idg; v.w *= idg;
  *(float4*)(hout + (((size_t)node) << 6) + fo) = v;
  if (vsave != nullptr && m == 14) vsave[node] = v.x;  // u-space col 56
}

__global__ __launch_bounds__(256) void k_hop(const float* __restrict__ hin,
                                             float* __restrict__ hout,
                                             const int* __restrict__ gcnt,
                                             const int* __restrict__ ellg,
                                             const float* __restrict__ ideg,
                                             float* __restrict__ vsave) {
  int wid = (blockIdx.x * blockDim.x + threadIdx.x) >> 6;
  int lane = threadIdx.x & 63;
  if (wid >= HALF_G) return;                 // wave-uniform exit
  int sub = lane >> 4, m = lane & 15, fo = m << 2;
  hop_group<true >(wid, hin, hout, gcnt, ellg, ideg, vsave, lane, sub, m, fo);
  hop_group<false>(wid + HALF_G, hin, hout, gcnt, ellg, ideg, vsave, lane, sub, m, fo);
}

// ---- collapse weights: M = W1W2W3W4; c1=b1'W2W3W4; c2=b2'W3W4; c3=b3'W4+b4

__global__ void k_weights(const float* __restrict__ W1, const float* __restrict__ b1,
                          const float* __restrict__ W2, const float* __restrict__ b2,
                          const float* __restrict__ W3, const float* __restrict__ b3,
                          const float* __restrict__ W4, const float* __restrict__ b4,
                          float* __restrict__ Mw, float* __restrict__ c1,
                          float* __restrict__ c2, float* __restrict__ c3) {
  __shared__ float t1[64], t2[64], t3[64];
  int m = blockIdx.x, tid = threadIdx.x;
  if (m < F_IN) {
    if (tid < 64) {
      float a = 0.f;
      for (int k = 0; k < 64; ++k) a = fmaf(W1[m * 64 + k], W2[k * 64 + tid], a);
      t1[tid] = a;
    }
    __syncthreads();
    if (tid < 64) {
      float a = 0.f;
      for (int k = 0; k < 64; ++k) a = fmaf(t1[k], W3[k * 64 + tid], a);
      t2[tid] = a;
    }
    __syncthreads();
    {
      float a = 0.f;
      for (int k = 0; k < 64; ++k) a = fmaf(t2[k], W4[k * 256 + tid], a);
      Mw[m * 256 + tid] = a;
    }
  } else {
    if (tid < 64) {
      float a = 0.f;
      for (int k = 0; k < 64; ++k) a = fmaf(b1[k], W2[k * 64 + tid], a);
      t1[tid] = a;
    }
    __syncthreads();
    if (tid < 64) {
      float a = 0.f, b = 0.f;
      for (int k = 0; k < 64; ++k) {
        float w3 = W3[k * 64 + tid];
        a = fmaf(t1[k], w3, a);
        b = fmaf(b2[k], w3, b);
      }
      t2[tid] = a; t3[tid] = b;
    }
    __syncthreads();
    {
      float a = 0.f, b = 0.f, c = 0.f;
      for (int k = 0; k < 64; ++k) {
        float w4 = W4[k * 256 + tid];
        a = fmaf(t2[k], w4, a);
        b = fmaf(t3[k], w4, b);
        c = fmaf(b3[k], w4, c);
      }
      c1[tid] = a; c2[tid] = b; c3[tid] = c + b4[tid];
    }
  }
}

// ---- epilogue: out = (sqd*y)@M + v6*c1 + v3*c2 + c3 ------------------------
// thread j owns col j; M[:,j] in 56 VGPRs; 16 independent acc chains.

__global__ __launch_bounds__(256) void k_final(const float* __restrict__ y,
                                               const float* __restrict__ v3u,
                                               const float* __restrict__ v6u,
                                               const float* __restrict__ sqd,
                                               const float* __restrict__ Mw,
                                               const float* __restrict__ c1,
                                               const float* __restrict__ c2,
                                               const float* __restrict__ c3,
                                               float* __restrict__ out) {
  __shared__ float4 yl[NB][16];          // 4.1 KB
  __shared__ float v3l[NB], v6l[NB];
  int tid = threadIdx.x;
  int j = tid;

  float4 Mreg[14];
#pragma unroll
  for (int k4 = 0; k4 < 14; ++k4) {
    Mreg[k4].x = Mw[(k4 * 4 + 0) * F_OUT + j];
    Mreg[k4].y = Mw[(k4 * 4 + 1) * F_OUT + j];
    Mreg[k4].z = Mw[(k4 * 4 + 2) * F_OUT + j];
    Mreg[k4].w = Mw[(k4 * 4 + 3) * F_OUT + j];
  }
  float C1 = c1[j], C2 = c2[j], C3 = c3[j];

  int n0 = blockIdx.x * NB;                // N_NODES % NB == 0
  {                                        // exactly one float4 per thread
    int i = tid;
    int nn = i >> 4, q = i & 15;
    float sq = sqd[n0 + nn];
    float4 v = *(const float4*)(y + ((size_t)(n0 + nn) << 6) + q * 4);
    v.x *= sq; v.y *= sq; v.z *= sq; v.w *= sq;
    yl[nn][q] = v;
  }
  if (tid < NB) {
    float sq = sqd[n0 + tid];
    v3l[tid] = v3u[n0 + tid] * sq;
    v6l[tid] = v6u[n0 + tid] * sq;
  }
  __syncthreads();

  float acc[NB];
#pragma unroll
  for (int nn = 0; nn < NB; ++nn)
    acc[nn] = fmaf(v6l[nn], C1, fmaf(v3l[nn], C2, C3));

#pragma unroll
  for (int k4 = 0; k4 < 14; ++k4) {
    float4 mk = Mreg[k4];
#pragma unroll
    for (int nn = 0; nn < NB; ++nn) {
      float4 yv = yl[nn][k4];
      acc[nn] = fmaf(yv.w, mk.w,
                fmaf(yv.z, mk.z,
                fmaf(yv.y, mk.y,
                fmaf(yv.x, mk.x, acc[nn]))));
    }
  }

#pragma unroll
  for (int nn = 0; nn < NB; ++nn)
    out[(size_t)(n0 + nn) * F_OUT + j] = acc[nn];
}

// ---- launch ---------------------------------------------------------------

extern "C" void kernel_launch(void* const* d_in, const int* in_sizes, int n_in,
                              void* d_out, int out_size, void* d_ws, size_t ws_size,
                              hipStream_t stream) {
  const float* x  = (const float*)d_in[0];
  const int*   ei = (const int*)d_in[1];
  const float* W1 = (const float*)d_in[2];
  const float* b1 = (const float*)d_in[3];
  const float* W2 = (const float*)d_in[4];
  const float* b2 = (const float*)d_in[5];
  const float* W3 = (const float*)d_in[6];
  const float* b3 = (const float*)d_in[7];
  const float* W4 = (const float*)d_in[8];
  const float* b4 = (const float*)d_in[9];
  float* out = (float*)d_out;

  char* ws = (char*)d_ws;
  size_t off = 0;
  auto take = [&](size_t bytes) -> void* {
    void* p = ws + off;
    off += (bytes + 255) & ~(size_t)255;
    return p;
  };
  int*   gcnt  = (int*)take((size_t)N_GROUPS * 4);
  float* dinv  = (float*)take((size_t)N_NODES * 4);
  float* ideg  = (float*)take((size_t)N_NODES * 4);
  float* sqd   = (float*)take((size_t)N_NODES * 4);
  float* v3    = (float*)take((size_t)N_NODES * 4);
  float* v6    = (float*)take((size_t)N_NODES * 4);
  int*   ellg  = (int*)take((size_t)N_GROUPS * GSLOTS * 4);       // 6.4 MB
  float* hA    = (float*)take((size_t)(N_NODES + 1) * F_PAD * 4); // + zero row
  float* hB    = (float*)take((size_t)(N_NODES + 1) * F_PAD * 4);
  float* Mw    = (float*)take((size_t)F_IN * F_OUT * 4);
  float* c1    = (float*)take((size_t)F_OUT * 4);
  float* c2    = (float*)take((size_t)F_OUT * 4);
  float* c3    = (float*)take((size_t)F_OUT * 4);

  (void)hipMemsetAsync(gcnt, 0, (size_t)N_GROUPS * 4, stream);
  (void)hipMemsetAsync(hA + (size_t)ZROW * F_PAD, 0, F_PAD * 4, stream);
  (void)hipMemsetAsync(hB + (size_t)ZROW * F_PAD, 0, F_PAD * 4, stream);
  k_fill<<<1024, 256, 0, stream>>>(ei, gcnt, ellg);
  k_self<<<(N_NODES + 255) / 256, 256, 0, stream>>>(gcnt, ellg);
  k_sort<<<(N_GROUPS * 64) / 256, 256, 0, stream>>>(gcnt, ellg, dinv, ideg, sqd);
  k_loadx<<<(N_NODES * F_PAD) / 256, 256, 0, stream>>>(x, dinv, hA);
  k_weights<<<F_IN + 1, 256, 0, stream>>>(W1, b1, W2, b2, W3, b3, W4, b4, Mw, c1, c2, c3);

  int hop_blocks = (HALF_G * 64 + 255) / 256;  // 1563 blocks = ~6252 waves
  float* src = hA;
  float* dst = hB;
  for (int hop = 1; hop <= 9; ++hop) {
    float* vs = (hop == 3) ? v3 : (hop == 6) ? v6 : nullptr;
    k_hop<<<hop_blocks, 256, 0, stream>>>(src, dst, gcnt, ellg, ideg, vs);
    float* t = src; src = dst; dst = t;
  }
  k_final<<<N_NODES / NB, 256, 0, stream>>>(src, v3, v6, sqd, Mw, c1, c2, c3, out);
}